// Round 7
// baseline (511.842 us; speedup 1.0000x reference)
//
#include <hip/hip_runtime.h>

#define NN 20000
#define TT 2
#define HH 128
#define LL 4
#define EE 320000
#define FF 514
#define CN 3
#define CG 2
#define EPS_MSG 1e-7f
#define MP 20096  // rows per ti-half, padded to multiple of 128

typedef __bf16 bf16x8 __attribute__((ext_vector_type(8)));
typedef __bf16 bf16x4 __attribute__((ext_vector_type(4)));
typedef __bf16 bf16x2 __attribute__((ext_vector_type(2)));
typedef float f32x4 __attribute__((ext_vector_type(4)));

struct __align__(8) Edge { int src; __bf16 ea0, ea1; };

// ---------------- wave helpers ----------------
__device__ inline float wave_sum(float v) {
#pragma unroll
  for (int off = 32; off; off >>= 1) v += __shfl_xor(v, off);
  return v;
}
__device__ inline float red16(float v) {  // reduce across fr = lane&15
  v += __shfl_xor(v, 1); v += __shfl_xor(v, 2);
  v += __shfl_xor(v, 4); v += __shfl_xor(v, 8);
  return v;
}

__device__ __forceinline__ void gload_lds16(const void* g, void* l) {
  __builtin_amdgcn_global_load_lds(
      (const __attribute__((address_space(1))) unsigned int*)g,
      (__attribute__((address_space(3))) unsigned int*)l, 16, 0, 0);
}

// ---------------- fused encoder GEMM + XCD-routed edge scatter --------------
// blocks [0, ENCB): C = A@BT + bias, dup to gm+MP (BM=64,BN=128,K=576)
// blocks [ENCB, ENCB+8*SCB): scatter; block handles edge slice (b-ENCB)>>3,
//   processes only edges whose dst-chunk == blockIdx%8 (XCD-local L2 writes).
#define ENCB (MP / 64)
#define SCB 2500
#define CHUNK 5000  // 2*NN/8 gnodes per XCD chunk
__global__ __launch_bounds__(256) void enc_scatter_kernel(
    const __bf16* __restrict__ A, const __bf16* __restrict__ BT,
    const float* __restrict__ bias, __bf16* __restrict__ C,
    const int* __restrict__ edge_index, const float* __restrict__ edge_attr,
    int* __restrict__ cursor, Edge* __restrict__ edges) {
  __shared__ __bf16 As[2][64][32];
  __shared__ __bf16 Bs[2][128][32];
  const int tid = threadIdx.x;
  if (blockIdx.x >= ENCB) {
    int chunk = blockIdx.x & 7;
    int i = ((blockIdx.x - ENCB) >> 3) * 256 + tid;
    if (i >= 2 * EE) return;
    int ti = (i >= EE) ? 1 : 0;
    int e = i - ti * EE;
    const int* srcp = edge_index + (size_t)ti * 2 * EE;
    int d = srcp[EE + e];
    int gnode = ti * NN + d;
    if (gnode / CHUNK != chunk) return;
    int s = srcp[e];
    float2 ea = ((const float2*)edge_attr)[(size_t)ti * EE + e];
    int pos = atomicAdd(&cursor[gnode], 1);
    Edge ed;
    ed.src = s + ti * MP;
    ed.ea0 = (__bf16)ea.x; ed.ea1 = (__bf16)ea.y;
    __builtin_memcpy(&edges[pos], &ed, sizeof(Edge));
    return;
  }
  const int K = 576;
  const int lane = tid & 63, w = tid >> 6;
  const int bm = blockIdx.x * 64;
  const int wr = (w >> 1) * 32, wc = (w & 1) * 64;
  const int fr = lane & 15, fq = lane >> 4;
  const int rowA = tid >> 2, chA = (tid & 3) * 8;
  const __bf16* Ab = A + (size_t)(bm + rowA) * K + chA;
  const __bf16* Bb = BT + (size_t)rowA * K + chA;
  const __bf16* Bb2 = Bb + (size_t)64 * K;
  f32x4 acc[2][4] = {};
#define STAGE(buf, k0)                                  \
  do {                                                  \
    gload_lds16(Ab + (k0), &As[buf][rowA][chA]);        \
    gload_lds16(Bb + (k0), &Bs[buf][rowA][chA]);        \
    gload_lds16(Bb2 + (k0), &Bs[buf][rowA + 64][chA]);  \
  } while (0)
  STAGE(0, 0);
  __syncthreads();
  int cur = 0;
  for (int k0 = 0; k0 < K; k0 += 32) {
    if (k0 + 32 < K) STAGE(cur ^ 1, k0 + 32);
    bf16x8 af[2], bq[4];
#pragma unroll
    for (int m = 0; m < 2; ++m)
      af[m] = *(const bf16x8*)&As[cur][wr + m * 16 + fr][fq * 8];
#pragma unroll
    for (int n = 0; n < 4; ++n)
      bq[n] = *(const bf16x8*)&Bs[cur][wc + n * 16 + fr][fq * 8];
#pragma unroll
    for (int m = 0; m < 2; ++m)
#pragma unroll
      for (int n = 0; n < 4; ++n)
        acc[m][n] =
            __builtin_amdgcn_mfma_f32_16x16x32_bf16(af[m], bq[n], acc[m][n], 0, 0, 0);
    __syncthreads();
    cur ^= 1;
  }
#undef STAGE
#pragma unroll
  for (int m = 0; m < 2; ++m) {
#pragma unroll
    for (int n = 0; n < 4; ++n) {
#pragma unroll
      for (int j = 0; j < 4; ++j) {
        int gm = bm + wr + m * 16 + fq * 4 + j;
        int gn = wc + n * 16 + fr;
        if (gm < NN) {
          __bf16 c = (__bf16)(acc[m][n][j] + bias[gn]);
          C[(size_t)gm * 128 + gn] = c;
          C[(size_t)(gm + MP) * 128 + gn] = c;
        }
      }
    }
  }
}

// ---------------- fused 256-wide GEMM (BM=64, BN=256, full row per wave) ----
// EPI 0: LN(c; g,be) -> relu -> bf16 out [rows][256]
// EPI 1: relu(c) -> @W2h[256,3] + b2h -> log_softmax -> f32 out [M][3]
template <int EPI>
__global__ __launch_bounds__(256) void gemm256(
    const __bf16* __restrict__ A, const __bf16* __restrict__ BT,
    const float* __restrict__ bias, const float* __restrict__ g,
    const float* __restrict__ be, const float* __restrict__ W2h,
    const float* __restrict__ b2h, void* __restrict__ outp, int M, int K) {
  __shared__ __bf16 As[2][64][32];
  __shared__ __bf16 Bs[2][256][32];
  const int tid = threadIdx.x;
  const int lane = tid & 63, w = tid >> 6;
  const int bm = blockIdx.x * 64;
  const int wr = w * 16;
  const int fr = lane & 15, fq = lane >> 4;
  const int rowA = tid >> 2, chA = (tid & 3) * 8;
  const __bf16* Ab = A + (size_t)(bm + rowA) * K + chA;
  const __bf16* Bb = BT + (size_t)rowA * K + chA;
  f32x4 acc[16] = {};

#define STG(buf, k0)                                                \
  do {                                                              \
    gload_lds16(Ab + (k0), &As[buf][rowA][chA]);                    \
    _Pragma("unroll") for (int r = 0; r < 4; ++r)                   \
        gload_lds16(Bb + (size_t)(r * 64) * K + (k0),               \
                    &Bs[buf][rowA + r * 64][chA]);                  \
  } while (0)

  STG(0, 0);
  __syncthreads();
  int cur = 0;
  for (int k0 = 0; k0 < K; k0 += 32) {
    if (k0 + 32 < K) STG(cur ^ 1, k0 + 32);
    bf16x8 af = *(const bf16x8*)&As[cur][wr + fr][fq * 8];
#pragma unroll
    for (int n = 0; n < 16; ++n) {
      bf16x8 bq = *(const bf16x8*)&Bs[cur][n * 16 + fr][fq * 8];
      acc[n] = __builtin_amdgcn_mfma_f32_16x16x32_bf16(af, bq, acc[n], 0, 0, 0);
    }
    __syncthreads();
    cur ^= 1;
  }
#undef STG

  float cb[16];
#pragma unroll
  for (int n = 0; n < 16; ++n) cb[n] = bias[n * 16 + fr];

  if constexpr (EPI == 0) {
    float gv[16], bev[16];
#pragma unroll
    for (int n = 0; n < 16; ++n) {
      gv[n] = g[n * 16 + fr];
      bev[n] = be[n * 16 + fr];
    }
    __bf16* outb = (__bf16*)outp;
#pragma unroll
    for (int j = 0; j < 4; ++j) {
      float cj[16], s = 0.f, s2 = 0.f;
#pragma unroll
      for (int n = 0; n < 16; ++n) {
        float c = acc[n][j] + cb[n];
        cj[n] = c; s += c; s2 += c * c;
      }
      s = red16(s); s2 = red16(s2);
      float mu = s * (1.f / 256);
      float var = fmaxf(s2 * (1.f / 256) - mu * mu, 0.f);
      float rr = rsqrtf(var + 1e-5f);
      int gm = bm + wr + fq * 4 + j;
      __bf16* op = outb + (size_t)gm * 256;
#pragma unroll
      for (int n = 0; n < 16; ++n) {
        float y = (cj[n] - mu) * rr * gv[n] + bev[n];
        op[n * 16 + fr] = (__bf16)fmaxf(y, 0.f);
      }
    }
  } else {
    float w0[16], w1[16], w2[16];
#pragma unroll
    for (int n = 0; n < 16; ++n) {
      int col = n * 16 + fr;
      w0[n] = W2h[col * 3 + 0];
      w1[n] = W2h[col * 3 + 1];
      w2[n] = W2h[col * 3 + 2];
    }
    float* outf = (float*)outp;
#pragma unroll
    for (int j = 0; j < 4; ++j) {
      float p0 = 0.f, p1 = 0.f, p2 = 0.f;
#pragma unroll
      for (int n = 0; n < 16; ++n) {
        float h = fmaxf(acc[n][j] + cb[n], 0.f);
        p0 += h * w0[n]; p1 += h * w1[n]; p2 += h * w2[n];
      }
      p0 = red16(p0); p1 = red16(p1); p2 = red16(p2);
      int gm = bm + wr + fq * 4 + j;
      if (fr == 0 && gm < M) {
        float l0 = p0 + b2h[0], l1 = p1 + b2h[1], l2 = p2 + b2h[2];
        float m = fmaxf(l0, fmaxf(l1, l2));
        float lse = m + logf(__expf(l0 - m) + __expf(l1 - m) + __expf(l2 - m));
        outf[(size_t)gm * 3 + 0] = l0 - lse;
        outf[(size_t)gm * 3 + 1] = l1 - lse;
        outf[(size_t)gm * 3 + 2] = l2 - lse;
      }
    }
  }
}

// ---------------- lin2 GEMM + residual + fused LayerNorm+ReLU --------------
// MODE 0: write xres (no add) + LN->relu->bf16 hb      (layer 0)
// MODE 1: add xres, write xres + LN->relu->bf16 hb     (layers 1..L-2)
// MODE 2: add xres, LN->relu->f32 emb[node*256+half*128+col] (last layer)
template <int MODE>
__global__ __launch_bounds__(256) void gemm_lin2(
    const __bf16* __restrict__ A, const __bf16* __restrict__ BT,
    const float* __restrict__ bias, float* __restrict__ xres,
    const float* __restrict__ g, const float* __restrict__ be,
    void* __restrict__ lnout) {
  __shared__ __bf16 As[2][64][32];
  __shared__ __bf16 Bs[2][128][32];
  __shared__ float redS[64][2], redS2[64][2];
  const int tid = threadIdx.x;
  const int lane = tid & 63, w = tid >> 6;
  const int bm = blockIdx.x * 64;
  const int wr = (w >> 1) * 32, wc = (w & 1) * 64;
  const int fr = lane & 15, fq = lane >> 4;
  const int rowA = tid >> 2, chA = (tid & 3) * 8;
  const __bf16* Ab = A + (size_t)(bm + rowA) * 256 + chA;
  const __bf16* Bb = BT + (size_t)rowA * 256 + chA;
  const __bf16* Bb2 = Bb + (size_t)64 * 256;
  f32x4 acc[2][4] = {};

#define STAGE(buf, k0)                                  \
  do {                                                  \
    gload_lds16(Ab + (k0), &As[buf][rowA][chA]);        \
    gload_lds16(Bb + (k0), &Bs[buf][rowA][chA]);        \
    gload_lds16(Bb2 + (k0), &Bs[buf][rowA + 64][chA]);  \
  } while (0)

  STAGE(0, 0);
  __syncthreads();
  int cur = 0;
  for (int k0 = 0; k0 < 256; k0 += 32) {
    if (k0 + 32 < 256) STAGE(cur ^ 1, k0 + 32);
    bf16x8 af[2], bq[4];
#pragma unroll
    for (int m = 0; m < 2; ++m)
      af[m] = *(const bf16x8*)&As[cur][wr + m * 16 + fr][fq * 8];
#pragma unroll
    for (int n = 0; n < 4; ++n)
      bq[n] = *(const bf16x8*)&Bs[cur][wc + n * 16 + fr][fq * 8];
#pragma unroll
    for (int m = 0; m < 2; ++m)
#pragma unroll
      for (int n = 0; n < 4; ++n)
        acc[m][n] =
            __builtin_amdgcn_mfma_f32_16x16x32_bf16(af[m], bq[n], acc[m][n], 0, 0, 0);
    __syncthreads();
    cur ^= 1;
  }
#undef STAGE

  float cv[2][4][4];
#pragma unroll
  for (int m = 0; m < 2; ++m) {
    int r0 = wr + m * 16 + fq * 4;
#pragma unroll
    for (int j = 0; j < 4; ++j) {
      int gm = bm + r0 + j;
      float s = 0.f, s2 = 0.f;
#pragma unroll
      for (int n = 0; n < 4; ++n) {
        float c = acc[m][n][j] + bias[wc + n * 16 + fr];
        if (MODE != 0) c += xres[(size_t)gm * 128 + wc + n * 16 + fr];
        cv[m][n][j] = c;
        s += c; s2 += c * c;
      }
      s = red16(s); s2 = red16(s2);
      if (fr == 0) {
        redS[r0 + j][w & 1] = s;
        redS2[r0 + j][w & 1] = s2;
      }
    }
  }
  __syncthreads();
#pragma unroll
  for (int m = 0; m < 2; ++m) {
    int r0 = wr + m * 16 + fq * 4;
#pragma unroll
    for (int j = 0; j < 4; ++j) {
      int r = r0 + j;
      int gm = bm + r;
      float S = redS[r][0] + redS[r][1];
      float S2 = redS2[r][0] + redS2[r][1];
      float mu = S * (1.f / 128);
      float var = fmaxf(S2 * (1.f / 128) - mu * mu, 0.f);
      float rr = rsqrtf(var + 1e-5f);
      if constexpr (MODE < 2) {
        float* xp = xres + (size_t)gm * 128;
        __bf16* hp = (__bf16*)lnout + (size_t)gm * 128;
#pragma unroll
        for (int n = 0; n < 4; ++n) {
          int col = wc + n * 16 + fr;
          float c = cv[m][n][j];
          xp[col] = c;
          float y = (c - mu) * rr * g[col] + be[col];
          hp[col] = (__bf16)fmaxf(y, 0.f);
        }
      } else {
        int half = gm >= MP;
        int node = gm - half * MP;
        if (node < NN) {
          float* ep = (float*)lnout + (size_t)node * 256 + half * 128;
#pragma unroll
          for (int n = 0; n < 4; ++n) {
            int col = wc + n * 16 + fr;
            float y = (cv[m][n][j] - mu) * rr * g[col] + be[col];
            ep[col] = fmaxf(y, 0.f);
          }
        }
      }
    }
  }
}

// ---------------- fused prologue (vectorized) -------------------------------
// ranges: [0,NF2B) nf bulk f32x2->bf16x2 | [..+PADB) nf zero-pad cols 514..575
//         [..+WTB) weight transpose-convert | [..+CNTB) degree count | [1] zero
struct WtDesc { const float* src; __bf16* dst; int K, N, Kpad; };
struct WtDescs { WtDesc d[10]; };
#define NF2B 20079  // ceil(NN*FF/2 / 256)
#define PADB 2422   // ceil(NN*31 / 256)  (31 bf16x2 pads per row)
#define WTB 2880
#define CNTB 2500

__global__ void prep_kernel(const float* __restrict__ nf_src,
                            __bf16* __restrict__ nf_dst, WtDescs descs,
                            const int* __restrict__ edge_index,
                            int* __restrict__ deg, float* __restrict__ gp_sum) {
  int b = blockIdx.x, tid = threadIdx.x;
  if (b < NF2B) {
    int i = b * 256 + tid;  // float2 index
    if (i >= NN * FF / 2) return;
    int row = i / 257;              // 514/2 = 257 float2 per row
    int col = (i - row * 257) * 2;  // even
    float2 v = ((const float2*)nf_src)[i];
    bf16x2 o; o[0] = (__bf16)v.x; o[1] = (__bf16)v.y;
    *(bf16x2*)(nf_dst + (size_t)row * 576 + col) = o;
  } else if (b < NF2B + PADB) {
    int i = (b - NF2B) * 256 + tid;
    if (i >= NN * 31) return;
    int row = i / 31, j = i - row * 31;
    bf16x2 z; z[0] = (__bf16)0.f; z[1] = (__bf16)0.f;
    *(bf16x2*)(nf_dst + (size_t)row * 576 + 514 + 2 * j) = z;
  } else if (b < NF2B + PADB + WTB) {
    int wb = b - NF2B - PADB;
    WtDesc de = descs.d[wb / 288];
    int idx = (wb % 288) * 256 + tid;
    if (idx >= de.N * de.Kpad) return;
    int n = idx / de.Kpad, k = idx - n * de.Kpad;
    float v = (k < de.K) ? de.src[(size_t)k * de.N + n] : 0.f;
    de.dst[idx] = (__bf16)v;
  } else if (b < NF2B + PADB + WTB + CNTB) {
    int i = (b - NF2B - PADB - WTB) * 256 + tid;
    if (i >= 2 * EE) return;
    int ti = (i >= EE) ? 1 : 0;
    int e = i - ti * EE;
    int d = edge_index[(size_t)ti * 2 * EE + EE + e];
    atomicAdd(&deg[ti * NN + d], 1);
  } else {
    gp_sum[tid] = 0.f;
  }
}

// ---------------- CSR scan (block per ti) ----------------
__global__ __launch_bounds__(1024) void scan2_kernel(
    const int* __restrict__ deg_all, int* __restrict__ rowptr,
    int* __restrict__ cursor) {
  const int ti = blockIdx.x;
  const int* deg = deg_all + ti * NN;
  __shared__ int sums[1024];
  int tid = threadIdx.x;
  int chunk = (NN + 1023) / 1024;
  int begin = tid * chunk, end = min(begin + chunk, NN);
  int s = 0;
  for (int i = begin; i < end; ++i) s += deg[i];
  sums[tid] = s;
  __syncthreads();
  for (int off = 1; off < 1024; off <<= 1) {
    int v = (tid >= off) ? sums[tid - off] : 0;
    __syncthreads();
    sums[tid] += v;
    __syncthreads();
  }
  int running = ti * EE + sums[tid] - s;
  for (int i = begin; i < end; ++i) {
    rowptr[ti * NN + i] = running;
    cursor[ti * NN + i] = running;
    running += deg[i];
  }
  if (tid == 0 && ti == 1) rowptr[2 * NN] = 2 * EE;
}

// ---------------- GENConv softmax aggregation + residual -------------------
// Half-wave per edge stream: lanes [0,32) even edges, [32,64) odd edges;
// lane covers 4 channels (bf16x4). 8-edge unroll = 4 gathers in flight/half.
__global__ __launch_bounds__(256) void agg_kernel(
    const __bf16* __restrict__ xin, const int* __restrict__ rowptr,
    const Edge* __restrict__ edges, const float* __restrict__ Wee,
    const float* __restrict__ bee, const float* __restrict__ tptr, int layer,
    __bf16* __restrict__ out) {
  int wave = threadIdx.x >> 6, lane = threadIdx.x & 63;
  int b = blockIdx.x;  // 10000 blocks
  int h8 = b & 7;
  int half = h8 >> 2;
  int within = (b >> 3) * 4 + (h8 & 3);   // 0..4999
  int node = within * 4 + wave;           // 0..19999
  int gnode = half * NN + node;
  int xrow = half * MP + node;
  float t = tptr[layer];
  int hh = lane >> 5, c32 = lane & 31, c0 = c32 * 4;
  float w0[4], w1[4], bv[4];
#pragma unroll
  for (int i = 0; i < 4; ++i) {
    w0[i] = Wee[c0 + i];
    w1[i] = Wee[HH + c0 + i];
    bv[i] = bee[c0 + i];
  }
  float den[4] = {}, num[4] = {};
  int e = rowptr[gnode], e1 = rowptr[gnode + 1];

#define MLP4(XV, ED)                                                \
  do {                                                              \
    float eax = (float)(ED).ea0, eay = (float)(ED).ea1;             \
    _Pragma("unroll") for (int i = 0; i < 4; ++i) {                 \
      float m = (float)(XV)[i] + eax * w0[i] + eay * w1[i] + bv[i]; \
      m = fmaxf(m, 0.f) + EPS_MSG;                                  \
      float ex = __expf(m * t);                                     \
      den[i] += ex; num[i] += m * ex;                               \
    }                                                               \
  } while (0)

  for (; e + 8 <= e1; e += 8) {
    Edge E0 = edges[e + hh], E1 = edges[e + 2 + hh];
    Edge E2 = edges[e + 4 + hh], E3 = edges[e + 6 + hh];
    bf16x4 x0 = *(const bf16x4*)(xin + (size_t)E0.src * HH + c0);
    bf16x4 x1 = *(const bf16x4*)(xin + (size_t)E1.src * HH + c0);
    bf16x4 x2 = *(const bf16x4*)(xin + (size_t)E2.src * HH + c0);
    bf16x4 x3 = *(const bf16x4*)(xin + (size_t)E3.src * HH + c0);
    MLP4(x0, E0); MLP4(x1, E1); MLP4(x2, E2); MLP4(x3, E3);
  }
  if (e + 4 <= e1) {
    Edge E0 = edges[e + hh], E1 = edges[e + 2 + hh];
    bf16x4 x0 = *(const bf16x4*)(xin + (size_t)E0.src * HH + c0);
    bf16x4 x1 = *(const bf16x4*)(xin + (size_t)E1.src * HH + c0);
    MLP4(x0, E0); MLP4(x1, E1);
    e += 4;
  }
  if (e + hh < e1) {
    Edge Ea = edges[e + hh];
    bf16x4 xa = *(const bf16x4*)(xin + (size_t)Ea.src * HH + c0);
    MLP4(xa, Ea);
  }
  if (e + 2 + hh < e1) {
    Edge Ea = edges[e + 2 + hh];
    bf16x4 xa = *(const bf16x4*)(xin + (size_t)Ea.src * HH + c0);
    MLP4(xa, Ea);
  }
#undef MLP4

#pragma unroll
  for (int i = 0; i < 4; ++i) {
    den[i] += __shfl_xor(den[i], 32);
    num[i] += __shfl_xor(num[i], 32);
  }
  if (hh == 0) {
    bf16x4 xr = *(const bf16x4*)(xin + (size_t)xrow * HH + c0);
    bf16x4 o;
#pragma unroll
    for (int i = 0; i < 4; ++i)
      o[i] = (__bf16)(num[i] / (den[i] + 1e-16f) + (float)xr[i]);
    *(bf16x4*)(out + (size_t)xrow * HH + c0) = o;
  }
}

// ---------------- fused channel attention (node + graph heads) -------------
__global__ __launch_bounds__(256) void attn2_kernel(
    const float* __restrict__ emb, const float* __restrict__ Wq_n,
    const float* __restrict__ Wk_n, const float* __restrict__ Wv_n,
    const float* __restrict__ gn, const float* __restrict__ Wq_g,
    const float* __restrict__ Wk_g, const float* __restrict__ Wv_g,
    const float* __restrict__ gg, __bf16* __restrict__ outn,
    float* __restrict__ outg, int nNodes) {
  int wave = threadIdx.x >> 6, lane = threadIdx.x & 63;
  int n = blockIdx.x * 4 + wave;
  if (n >= nNodes) return;
  int c0 = lane * 2;
  const float* base = emb + (size_t)n * (2 * HH);
  float2 x0 = *(const float2*)(base + c0);
  float2 x1 = *(const float2*)(base + HH + c0);

#define ATTN_BODY(Wq, Wk, Wv, GAM, O0A, O0B, O1A, O1B)                        \
  {                                                                           \
    float gamma = *(GAM);                                                     \
    float wq00 = Wq[0], wq01 = Wq[1], wq10 = Wq[2], wq11 = Wq[3];             \
    float wk00 = Wk[0], wk01 = Wk[1], wk10 = Wk[2], wk11 = Wk[3];             \
    float wv00 = Wv[0], wv01 = Wv[1], wv10 = Wv[2], wv11 = Wv[3];             \
    float q0a = wq00 * x0.x + wq01 * x1.x, q0b = wq00 * x0.y + wq01 * x1.y;   \
    float q1a = wq10 * x0.x + wq11 * x1.x, q1b = wq10 * x0.y + wq11 * x1.y;   \
    float k0a = wk00 * x0.x + wk01 * x1.x, k0b = wk00 * x0.y + wk01 * x1.y;   \
    float k1a = wk10 * x0.x + wk11 * x1.x, k1b = wk10 * x0.y + wk11 * x1.y;   \
    float v0a = wv00 * x0.x + wv01 * x1.x, v0b = wv00 * x0.y + wv01 * x1.y;   \
    float v1a = wv10 * x0.x + wv11 * x1.x, v1b = wv10 * x0.y + wv11 * x1.y;   \
    float s00 = wave_sum(q0a * k0a + q0b * k0b);                              \
    float s01 = wave_sum(q0a * k1a + q0b * k1b);                              \
    float s10 = wave_sum(q1a * k0a + q1b * k0b);                              \
    float s11 = wave_sum(q1a * k1a + q1b * k1b);                              \
    float m0 = fmaxf(s00, s01);                                               \
    float e00 = __expf(s00 - m0), e01 = __expf(s01 - m0);                     \
    float i0 = 1.f / (e00 + e01);                                             \
    float a00 = e00 * i0, a01 = e01 * i0;                                     \
    float m1 = fmaxf(s10, s11);                                               \
    float e10 = __expf(s10 - m1), e11 = __expf(s11 - m1);                     \
    float i1 = 1.f / (e10 + e11);                                             \
    float a10 = e10 * i1, a11 = e11 * i1;                                     \
    O0A = gamma * (a00 * v0a + a01 * v1a) + x0.x;                             \
    O0B = gamma * (a00 * v0b + a01 * v1b) + x0.y;                             \
    O1A = gamma * (a10 * v0a + a11 * v1a) + x1.x;                             \
    O1B = gamma * (a10 * v0b + a11 * v1b) + x1.y;                             \
  }

  float n0a, n0b, n1a, n1b;
  ATTN_BODY(Wq_n, Wk_n, Wv_n, gn, n0a, n0b, n1a, n1b);
  __bf16* opn = outn + (size_t)n * (2 * HH);
  bf16x2 t0; t0[0] = (__bf16)n0a; t0[1] = (__bf16)n0b;
  bf16x2 t1; t1[0] = (__bf16)n1a; t1[1] = (__bf16)n1b;
  *(bf16x2*)(opn + c0) = t0;
  *(bf16x2*)(opn + HH + c0) = t1;

  float g0a, g0b, g1a, g1b;
  ATTN_BODY(Wq_g, Wk_g, Wv_g, gg, g0a, g0b, g1a, g1b);
  float* opg = outg + (size_t)n * (2 * HH);
  *(float2*)(opg + c0) = make_float2(g0a, g0b);
  *(float2*)(opg + HH + c0) = make_float2(g1a, g1b);
#undef ATTN_BODY
}

// ---------------- mean pool ----------------
__global__ __launch_bounds__(256) void pool_kernel(const float* __restrict__ gbuf,
                                                   float* __restrict__ gp_sum, int nNodes) {
  int c = threadIdx.x;
  float s = 0.f;
  for (int r = blockIdx.x; r < nNodes; r += gridDim.x) s += gbuf[(size_t)r * 256 + c];
  atomicAdd(&gp_sum[c], s);
}

// ---------------- graph head (single block) ----------------
__global__ __launch_bounds__(256) void graph_head_kernel(
    const float* __restrict__ gp_sum, const float* __restrict__ Wg1,
    const float* __restrict__ bg1, const float* __restrict__ Wg2,
    const float* __restrict__ bg2, float* __restrict__ outp, float invN) {
  __shared__ float gp[256];
  __shared__ float h1[256];
  __shared__ float lg[2];
  int tid = threadIdx.x;
  gp[tid] = gp_sum[tid] * invN;
  __syncthreads();
  float acc = bg1[tid];
  for (int k = 0; k < 256; ++k) acc += gp[k] * Wg1[k * 256 + tid];
  h1[tid] = fmaxf(acc, 0.f);
  __syncthreads();
  if (tid < 2) {
    float l = bg2[tid];
    for (int c = 0; c < 256; ++c) l += h1[c] * Wg2[c * 2 + tid];
    lg[tid] = l;
  }
  __syncthreads();
  if (tid == 0) {
    float m = fmaxf(lg[0], lg[1]);
    float lse = m + logf(__expf(lg[0] - m) + __expf(lg[1] - m));
    outp[0] = lg[0] - lse;
    outp[1] = lg[1] - lse;
  }
}

// ---------------- launch ----------------
extern "C" void kernel_launch(void* const* d_in, const int* in_sizes, int n_in,
                              void* d_out, int out_size, void* d_ws, size_t ws_size,
                              hipStream_t stream) {
  (void)in_sizes; (void)n_in; (void)out_size; (void)ws_size;
  const float* node_feature = (const float*)d_in[0];
  const int* edge_index = (const int*)d_in[1];
  const float* edge_attr = (const float*)d_in[2];
  const float* Wne = (const float*)d_in[3];
  const float* bne = (const float*)d_in[4];
  const float* Wee = (const float*)d_in[5];
  const float* bee = (const float*)d_in[6];
  const float* W1 = (const float*)d_in[7];
  const float* b1 = (const float*)d_in[8];
  const float* g1 = (const float*)d_in[9];
  const float* be1 = (const float*)d_in[10];
  const float* W2 = (const float*)d_in[11];
  const float* b2 = (const float*)d_in[12];
  const float* dg = (const float*)d_in[13];
  const float* db = (const float*)d_in[14];
  const float* tpar = (const float*)d_in[15];
  const float* Wq_n = (const float*)d_in[16];
  const float* Wk_n = (const float*)d_in[17];
  const float* Wv_n = (const float*)d_in[18];
  const float* gamma_n = (const float*)d_in[19];
  const float* Wn1 = (const float*)d_in[20];
  const float* bn1 = (const float*)d_in[21];
  const float* Wn2 = (const float*)d_in[22];
  const float* bn2 = (const float*)d_in[23];
  const float* Wq_g = (const float*)d_in[24];
  const float* Wk_g = (const float*)d_in[25];
  const float* Wv_g = (const float*)d_in[26];
  const float* gamma_g = (const float*)d_in[27];
  const float* Wg1 = (const float*)d_in[28];
  const float* bg1 = (const float*)d_in[29];
  const float* Wg2 = (const float*)d_in[30];
  const float* bg2 = (const float*)d_in[31];
  float* out = (float*)d_out;

  // ---- workspace carve-out (256B-aligned regions) ----
  char* pc = (char*)d_ws;
  auto alloc = [&](size_t bytes) {
    char* r = pc;
    pc += (bytes + 255) & ~(size_t)255;
    return r;
  };
  float* xbuf = (float*)alloc((size_t)2 * MP * HH * 4);       // f32 residual
  __bf16* hbuf_b = (__bf16*)alloc((size_t)2 * MP * HH * 2);   // LN'd agg input
  __bf16* t256_b = (__bf16*)alloc((size_t)2 * MP * 256 * 2);  // lin1+LN out
  float* emb = (float*)alloc((size_t)NN * 2 * HH * 4);        // [N,T,H] f32
  __bf16* aggout_b = (__bf16*)alloc((size_t)2 * MP * HH * 2); // agg out
  __bf16* nf_b = (__bf16*)emb;  // 23.0MB <= emb(20.5)+aggout(10.3)
  __bf16* attnb = t256_b;       // alias: node-attn out (after last lin2)
  float* buf2 = xbuf;           // alias: graph-attn out (after last lin2)
  __bf16* wt_ne = (__bf16*)alloc((size_t)128 * 576 * 2);
  __bf16* wt1 = (__bf16*)alloc((size_t)4 * 256 * 128 * 2);
  __bf16* wt2 = (__bf16*)alloc((size_t)4 * 128 * 256 * 2);
  __bf16* wtn1 = (__bf16*)alloc((size_t)256 * 256 * 2);
  float* gp_sum = (float*)alloc(256 * 4);
  int* deg = (int*)alloc((size_t)2 * NN * 4);
  int* cursor = (int*)alloc((size_t)2 * NN * 4);
  int* rowptr = (int*)alloc((size_t)(2 * NN + 2) * 4);
  Edge* edges = (Edge*)alloc((size_t)2 * EE * 8);

  const int gRows2 = 2 * MP / 64;  // 628 row-blocks, stacked GEMMs

  WtDescs wd;
  wd.d[0] = {Wne, wt_ne, FF, HH, 576};
  for (int l = 0; l < 4; ++l)
    wd.d[1 + l] = {W1 + (size_t)l * HH * 256, wt1 + (size_t)l * 256 * HH, HH, 256, HH};
  for (int l = 0; l < 4; ++l)
    wd.d[5 + l] = {W2 + (size_t)l * 256 * HH, wt2 + (size_t)l * HH * 256, 256, HH, 256};
  wd.d[9] = {Wn1, wtn1, 256, 256, 256};

  // prologue: deg zero; converts (vectorized) + degree count + gp_sum zero
  hipMemsetAsync(deg, 0, 2 * NN * sizeof(int), stream);
  prep_kernel<<<NF2B + PADB + WTB + CNTB + 1, 256, 0, stream>>>(
      node_feature, nf_b, wd, edge_index, deg, gp_sum);
  scan2_kernel<<<2, 1024, 0, stream>>>(deg, rowptr, cursor);
  // encoder GEMM (dup to both halves) fused with XCD-routed edge scatter
  enc_scatter_kernel<<<ENCB + 8 * SCB, 256, 0, stream>>>(
      nf_b, wt_ne, bne, hbuf_b, edge_index, edge_attr, cursor, edges);

  // layer loop, both ti at once
  for (int l = 0; l < LL; ++l) {
    agg_kernel<<<2 * NN / 4, 256, 0, stream>>>(hbuf_b, rowptr, edges, Wee, bee, tpar,
                                               l, aggout_b);
    gemm256<0><<<gRows2, 256, 0, stream>>>(aggout_b, wt1 + (size_t)l * 256 * HH,
                                           b1 + l * 2 * HH, g1 + l * 2 * HH,
                                           be1 + l * 2 * HH, nullptr, nullptr, t256_b,
                                           2 * MP, HH);
    const __bf16* w2l = wt2 + (size_t)l * HH * 256;
    const float* b2l = b2 + l * HH;
    if (l == 0)
      gemm_lin2<0><<<gRows2, 256, 0, stream>>>(t256_b, w2l, b2l, xbuf, dg + 1 * HH,
                                               db + 1 * HH, hbuf_b);
    else if (l < LL - 1)
      gemm_lin2<1><<<gRows2, 256, 0, stream>>>(t256_b, w2l, b2l, xbuf,
                                               dg + (l + 1) * HH, db + (l + 1) * HH,
                                               hbuf_b);
    else
      gemm_lin2<2><<<gRows2, 256, 0, stream>>>(t256_b, w2l, b2l, xbuf, dg, db, emb);
  }

  // fused node+graph attention (one emb read)
  attn2_kernel<<<(NN + 3) / 4, 256, 0, stream>>>(emb, Wq_n, Wk_n, Wv_n, gamma_n,
                                                 Wq_g, Wk_g, Wv_g, gamma_g, attnb,
                                                 buf2, NN);
  // node head: lin1+relu+Wn2+log_softmax fused
  gemm256<1><<<MP / 64, 256, 0, stream>>>(attnb, wtn1, bn1, nullptr, nullptr, Wn2,
                                          bn2, out, NN, 256);
  // graph head
  pool_kernel<<<128, 256, 0, stream>>>(buf2, gp_sum, NN);
  graph_head_kernel<<<1, 256, 0, stream>>>(gp_sum, Wg1, bg1, Wg2, bg2,
                                           out + (size_t)NN * CN, 1.0f / NN);
}

// Round 8
// 487.923 us; speedup vs baseline: 1.0490x; 1.0490x over previous
//
#include <hip/hip_runtime.h>

#define NN 20000
#define TT 2
#define HH 128
#define LL 4
#define EE 320000
#define FF 514
#define CN 3
#define CG 2
#define EPS_MSG 1e-7f
#define MP 20096  // rows per ti-half, padded to multiple of 128

typedef __bf16 bf16x8 __attribute__((ext_vector_type(8)));
typedef __bf16 bf16x4 __attribute__((ext_vector_type(4)));
typedef __bf16 bf16x2 __attribute__((ext_vector_type(2)));
typedef float f32x4 __attribute__((ext_vector_type(4)));

struct __align__(8) Edge { int src; __bf16 ea0, ea1; };

// ---------------- wave helpers ----------------
__device__ inline float wave_sum(float v) {
#pragma unroll
  for (int off = 32; off; off >>= 1) v += __shfl_xor(v, off);
  return v;
}
__device__ inline float red16(float v) {  // reduce across fr = lane&15
  v += __shfl_xor(v, 1); v += __shfl_xor(v, 2);
  v += __shfl_xor(v, 4); v += __shfl_xor(v, 8);
  return v;
}

__device__ __forceinline__ float fexp2(float x) {
#if __has_builtin(__builtin_amdgcn_exp2f)
  return __builtin_amdgcn_exp2f(x);
#else
  return exp2f(x);
#endif
}

__device__ __forceinline__ void gload_lds16(const void* g, void* l) {
  __builtin_amdgcn_global_load_lds(
      (const __attribute__((address_space(1))) unsigned int*)g,
      (__attribute__((address_space(3))) unsigned int*)l, 16, 0, 0);
}

// ---------------- fused encoder GEMM + XCD-routed edge scatter --------------
#define ENCB (MP / 64)
#define SCB 2500
#define CHUNK 5000  // 2*NN/8 gnodes per XCD chunk
__global__ __launch_bounds__(256) void enc_scatter_kernel(
    const __bf16* __restrict__ A, const __bf16* __restrict__ BT,
    const float* __restrict__ bias, __bf16* __restrict__ C,
    const int* __restrict__ edge_index, const float* __restrict__ edge_attr,
    int* __restrict__ cursor, Edge* __restrict__ edges) {
  __shared__ __bf16 As[2][64][32];
  __shared__ __bf16 Bs[2][128][32];
  const int tid = threadIdx.x;
  if (blockIdx.x >= ENCB) {
    int chunk = blockIdx.x & 7;
    int i = ((blockIdx.x - ENCB) >> 3) * 256 + tid;
    if (i >= 2 * EE) return;
    int ti = (i >= EE) ? 1 : 0;
    int e = i - ti * EE;
    const int* srcp = edge_index + (size_t)ti * 2 * EE;
    int d = srcp[EE + e];
    int gnode = ti * NN + d;
    if (gnode / CHUNK != chunk) return;
    int s = srcp[e];
    float2 ea = ((const float2*)edge_attr)[(size_t)ti * EE + e];
    int pos = atomicAdd(&cursor[gnode], 1);
    Edge ed;
    ed.src = s + ti * MP;
    ed.ea0 = (__bf16)ea.x; ed.ea1 = (__bf16)ea.y;
    __builtin_memcpy(&edges[pos], &ed, sizeof(Edge));
    return;
  }
  const int K = 576;
  const int lane = tid & 63, w = tid >> 6;
  const int bm = blockIdx.x * 64;
  const int wr = (w >> 1) * 32, wc = (w & 1) * 64;
  const int fr = lane & 15, fq = lane >> 4;
  const int rowA = tid >> 2, chA = (tid & 3) * 8;
  const __bf16* Ab = A + (size_t)(bm + rowA) * K + chA;
  const __bf16* Bb = BT + (size_t)rowA * K + chA;
  const __bf16* Bb2 = Bb + (size_t)64 * K;
  f32x4 acc[2][4] = {};
#define STAGE(buf, k0)                                  \
  do {                                                  \
    gload_lds16(Ab + (k0), &As[buf][rowA][chA]);        \
    gload_lds16(Bb + (k0), &Bs[buf][rowA][chA]);        \
    gload_lds16(Bb2 + (k0), &Bs[buf][rowA + 64][chA]);  \
  } while (0)
  STAGE(0, 0);
  __syncthreads();
  int cur = 0;
  for (int k0 = 0; k0 < K; k0 += 32) {
    if (k0 + 32 < K) STAGE(cur ^ 1, k0 + 32);
    bf16x8 af[2], bq[4];
#pragma unroll
    for (int m = 0; m < 2; ++m)
      af[m] = *(const bf16x8*)&As[cur][wr + m * 16 + fr][fq * 8];
#pragma unroll
    for (int n = 0; n < 4; ++n)
      bq[n] = *(const bf16x8*)&Bs[cur][wc + n * 16 + fr][fq * 8];
#pragma unroll
    for (int m = 0; m < 2; ++m)
#pragma unroll
      for (int n = 0; n < 4; ++n)
        acc[m][n] =
            __builtin_amdgcn_mfma_f32_16x16x32_bf16(af[m], bq[n], acc[m][n], 0, 0, 0);
    __syncthreads();
    cur ^= 1;
  }
#undef STAGE
#pragma unroll
  for (int m = 0; m < 2; ++m) {
#pragma unroll
    for (int n = 0; n < 4; ++n) {
#pragma unroll
      for (int j = 0; j < 4; ++j) {
        int gm = bm + wr + m * 16 + fq * 4 + j;
        int gn = wc + n * 16 + fr;
        if (gm < NN) {
          __bf16 c = (__bf16)(acc[m][n][j] + bias[gn]);
          C[(size_t)gm * 128 + gn] = c;
          C[(size_t)(gm + MP) * 128 + gn] = c;
        }
      }
    }
  }
}

// ---------------- fused 256-wide GEMM (BM=64, BN=256, full row per wave) ----
template <int EPI>
__global__ __launch_bounds__(256) void gemm256(
    const __bf16* __restrict__ A, const __bf16* __restrict__ BT,
    const float* __restrict__ bias, const float* __restrict__ g,
    const float* __restrict__ be, const float* __restrict__ W2h,
    const float* __restrict__ b2h, void* __restrict__ outp, int M, int K) {
  __shared__ __bf16 As[2][64][32];
  __shared__ __bf16 Bs[2][256][32];
  const int tid = threadIdx.x;
  const int lane = tid & 63, w = tid >> 6;
  const int bm = blockIdx.x * 64;
  const int wr = w * 16;
  const int fr = lane & 15, fq = lane >> 4;
  const int rowA = tid >> 2, chA = (tid & 3) * 8;
  const __bf16* Ab = A + (size_t)(bm + rowA) * K + chA;
  const __bf16* Bb = BT + (size_t)rowA * K + chA;
  f32x4 acc[16] = {};

#define STG(buf, k0)                                                \
  do {                                                              \
    gload_lds16(Ab + (k0), &As[buf][rowA][chA]);                    \
    _Pragma("unroll") for (int r = 0; r < 4; ++r)                   \
        gload_lds16(Bb + (size_t)(r * 64) * K + (k0),               \
                    &Bs[buf][rowA + r * 64][chA]);                  \
  } while (0)

  STG(0, 0);
  __syncthreads();
  int cur = 0;
  for (int k0 = 0; k0 < K; k0 += 32) {
    if (k0 + 32 < K) STG(cur ^ 1, k0 + 32);
    bf16x8 af = *(const bf16x8*)&As[cur][wr + fr][fq * 8];
#pragma unroll
    for (int n = 0; n < 16; ++n) {
      bf16x8 bq = *(const bf16x8*)&Bs[cur][n * 16 + fr][fq * 8];
      acc[n] = __builtin_amdgcn_mfma_f32_16x16x32_bf16(af, bq, acc[n], 0, 0, 0);
    }
    __syncthreads();
    cur ^= 1;
  }
#undef STG

  float cb[16];
#pragma unroll
  for (int n = 0; n < 16; ++n) cb[n] = bias[n * 16 + fr];

  if constexpr (EPI == 0) {
    float gv[16], bev[16];
#pragma unroll
    for (int n = 0; n < 16; ++n) {
      gv[n] = g[n * 16 + fr];
      bev[n] = be[n * 16 + fr];
    }
    __bf16* outb = (__bf16*)outp;
#pragma unroll
    for (int j = 0; j < 4; ++j) {
      float cj[16], s = 0.f, s2 = 0.f;
#pragma unroll
      for (int n = 0; n < 16; ++n) {
        float c = acc[n][j] + cb[n];
        cj[n] = c; s += c; s2 += c * c;
      }
      s = red16(s); s2 = red16(s2);
      float mu = s * (1.f / 256);
      float var = fmaxf(s2 * (1.f / 256) - mu * mu, 0.f);
      float rr = rsqrtf(var + 1e-5f);
      int gm = bm + wr + fq * 4 + j;
      __bf16* op = outb + (size_t)gm * 256;
#pragma unroll
      for (int n = 0; n < 16; ++n) {
        float y = (cj[n] - mu) * rr * gv[n] + bev[n];
        op[n * 16 + fr] = (__bf16)fmaxf(y, 0.f);
      }
    }
  } else {
    float w0[16], w1[16], w2[16];
#pragma unroll
    for (int n = 0; n < 16; ++n) {
      int col = n * 16 + fr;
      w0[n] = W2h[col * 3 + 0];
      w1[n] = W2h[col * 3 + 1];
      w2[n] = W2h[col * 3 + 2];
    }
    float* outf = (float*)outp;
#pragma unroll
    for (int j = 0; j < 4; ++j) {
      float p0 = 0.f, p1 = 0.f, p2 = 0.f;
#pragma unroll
      for (int n = 0; n < 16; ++n) {
        float h = fmaxf(acc[n][j] + cb[n], 0.f);
        p0 += h * w0[n]; p1 += h * w1[n]; p2 += h * w2[n];
      }
      p0 = red16(p0); p1 = red16(p1); p2 = red16(p2);
      int gm = bm + wr + fq * 4 + j;
      if (fr == 0 && gm < M) {
        float l0 = p0 + b2h[0], l1 = p1 + b2h[1], l2 = p2 + b2h[2];
        float m = fmaxf(l0, fmaxf(l1, l2));
        float lse = m + logf(__expf(l0 - m) + __expf(l1 - m) + __expf(l2 - m));
        outf[(size_t)gm * 3 + 0] = l0 - lse;
        outf[(size_t)gm * 3 + 1] = l1 - lse;
        outf[(size_t)gm * 3 + 2] = l2 - lse;
      }
    }
  }
}

// ---------------- lin2 GEMM + residual + fused LayerNorm+ReLU --------------
template <int MODE>
__global__ __launch_bounds__(256) void gemm_lin2(
    const __bf16* __restrict__ A, const __bf16* __restrict__ BT,
    const float* __restrict__ bias, float* __restrict__ xres,
    const float* __restrict__ g, const float* __restrict__ be,
    void* __restrict__ lnout) {
  __shared__ __bf16 As[2][64][32];
  __shared__ __bf16 Bs[2][128][32];
  __shared__ float redS[64][2], redS2[64][2];
  const int tid = threadIdx.x;
  const int lane = tid & 63, w = tid >> 6;
  const int bm = blockIdx.x * 64;
  const int wr = (w >> 1) * 32, wc = (w & 1) * 64;
  const int fr = lane & 15, fq = lane >> 4;
  const int rowA = tid >> 2, chA = (tid & 3) * 8;
  const __bf16* Ab = A + (size_t)(bm + rowA) * 256 + chA;
  const __bf16* Bb = BT + (size_t)rowA * 256 + chA;
  const __bf16* Bb2 = Bb + (size_t)64 * 256;
  f32x4 acc[2][4] = {};

#define STAGE(buf, k0)                                  \
  do {                                                  \
    gload_lds16(Ab + (k0), &As[buf][rowA][chA]);        \
    gload_lds16(Bb + (k0), &Bs[buf][rowA][chA]);        \
    gload_lds16(Bb2 + (k0), &Bs[buf][rowA + 64][chA]);  \
  } while (0)

  STAGE(0, 0);
  __syncthreads();
  int cur = 0;
  for (int k0 = 0; k0 < 256; k0 += 32) {
    if (k0 + 32 < 256) STAGE(cur ^ 1, k0 + 32);
    bf16x8 af[2], bq[4];
#pragma unroll
    for (int m = 0; m < 2; ++m)
      af[m] = *(const bf16x8*)&As[cur][wr + m * 16 + fr][fq * 8];
#pragma unroll
    for (int n = 0; n < 4; ++n)
      bq[n] = *(const bf16x8*)&Bs[cur][wc + n * 16 + fr][fq * 8];
#pragma unroll
    for (int m = 0; m < 2; ++m)
#pragma unroll
      for (int n = 0; n < 4; ++n)
        acc[m][n] =
            __builtin_amdgcn_mfma_f32_16x16x32_bf16(af[m], bq[n], acc[m][n], 0, 0, 0);
    __syncthreads();
    cur ^= 1;
  }
#undef STAGE

  float cv[2][4][4];
#pragma unroll
  for (int m = 0; m < 2; ++m) {
    int r0 = wr + m * 16 + fq * 4;
#pragma unroll
    for (int j = 0; j < 4; ++j) {
      int gm = bm + r0 + j;
      float s = 0.f, s2 = 0.f;
#pragma unroll
      for (int n = 0; n < 4; ++n) {
        float c = acc[m][n][j] + bias[wc + n * 16 + fr];
        if (MODE != 0) c += xres[(size_t)gm * 128 + wc + n * 16 + fr];
        cv[m][n][j] = c;
        s += c; s2 += c * c;
      }
      s = red16(s); s2 = red16(s2);
      if (fr == 0) {
        redS[r0 + j][w & 1] = s;
        redS2[r0 + j][w & 1] = s2;
      }
    }
  }
  __syncthreads();
#pragma unroll
  for (int m = 0; m < 2; ++m) {
    int r0 = wr + m * 16 + fq * 4;
#pragma unroll
    for (int j = 0; j < 4; ++j) {
      int r = r0 + j;
      int gm = bm + r;
      float S = redS[r][0] + redS[r][1];
      float S2 = redS2[r][0] + redS2[r][1];
      float mu = S * (1.f / 128);
      float var = fmaxf(S2 * (1.f / 128) - mu * mu, 0.f);
      float rr = rsqrtf(var + 1e-5f);
      if constexpr (MODE < 2) {
        float* xp = xres + (size_t)gm * 128;
        __bf16* hp = (__bf16*)lnout + (size_t)gm * 128;
#pragma unroll
        for (int n = 0; n < 4; ++n) {
          int col = wc + n * 16 + fr;
          float c = cv[m][n][j];
          xp[col] = c;
          float y = (c - mu) * rr * g[col] + be[col];
          hp[col] = (__bf16)fmaxf(y, 0.f);
        }
      } else {
        int half = gm >= MP;
        int node = gm - half * MP;
        if (node < NN) {
          float* ep = (float*)lnout + (size_t)node * 256 + half * 128;
#pragma unroll
          for (int n = 0; n < 4; ++n) {
            int col = wc + n * 16 + fr;
            float y = (cv[m][n][j] - mu) * rr * g[col] + be[col];
            ep[col] = fmaxf(y, 0.f);
          }
        }
      }
    }
  }
}

// ---------------- fused prologue (vectorized) -------------------------------
struct WtDesc { const float* src; __bf16* dst; int K, N, Kpad; };
struct WtDescs { WtDesc d[10]; };
#define NF2B 20079  // ceil(NN*FF/2 / 256)
#define PADB 2422   // ceil(NN*31 / 256)
#define WTB 2880
#define CNTB 2500

__global__ void prep_kernel(const float* __restrict__ nf_src,
                            __bf16* __restrict__ nf_dst, WtDescs descs,
                            const int* __restrict__ edge_index,
                            int* __restrict__ deg, float* __restrict__ gp_sum) {
  int b = blockIdx.x, tid = threadIdx.x;
  if (b < NF2B) {
    int i = b * 256 + tid;  // float2 index
    if (i >= NN * FF / 2) return;
    int row = i / 257;
    int col = (i - row * 257) * 2;
    float2 v = ((const float2*)nf_src)[i];
    bf16x2 o; o[0] = (__bf16)v.x; o[1] = (__bf16)v.y;
    *(bf16x2*)(nf_dst + (size_t)row * 576 + col) = o;
  } else if (b < NF2B + PADB) {
    int i = (b - NF2B) * 256 + tid;
    if (i >= NN * 31) return;
    int row = i / 31, j = i - row * 31;
    bf16x2 z; z[0] = (__bf16)0.f; z[1] = (__bf16)0.f;
    *(bf16x2*)(nf_dst + (size_t)row * 576 + 514 + 2 * j) = z;
  } else if (b < NF2B + PADB + WTB) {
    int wb = b - NF2B - PADB;
    WtDesc de = descs.d[wb / 288];
    int idx = (wb % 288) * 256 + tid;
    if (idx >= de.N * de.Kpad) return;
    int n = idx / de.Kpad, k = idx - n * de.Kpad;
    float v = (k < de.K) ? de.src[(size_t)k * de.N + n] : 0.f;
    de.dst[idx] = (__bf16)v;
  } else if (b < NF2B + PADB + WTB + CNTB) {
    int i = (b - NF2B - PADB - WTB) * 256 + tid;
    if (i >= 2 * EE) return;
    int ti = (i >= EE) ? 1 : 0;
    int e = i - ti * EE;
    int d = edge_index[(size_t)ti * 2 * EE + EE + e];
    atomicAdd(&deg[ti * NN + d], 1);
  } else {
    gp_sum[tid] = 0.f;
  }
}

// ---------------- CSR scan (block per ti) ----------------
__global__ __launch_bounds__(1024) void scan2_kernel(
    const int* __restrict__ deg_all, int* __restrict__ rowptr,
    int* __restrict__ cursor) {
  const int ti = blockIdx.x;
  const int* deg = deg_all + ti * NN;
  __shared__ int sums[1024];
  int tid = threadIdx.x;
  int chunk = (NN + 1023) / 1024;
  int begin = tid * chunk, end = min(begin + chunk, NN);
  int s = 0;
  for (int i = begin; i < end; ++i) s += deg[i];
  sums[tid] = s;
  __syncthreads();
  for (int off = 1; off < 1024; off <<= 1) {
    int v = (tid >= off) ? sums[tid - off] : 0;
    __syncthreads();
    sums[tid] += v;
    __syncthreads();
  }
  int running = ti * EE + sums[tid] - s;
  for (int i = begin; i < end; ++i) {
    rowptr[ti * NN + i] = running;
    cursor[ti * NN + i] = running;
    running += deg[i];
  }
  if (tid == 0 && ti == 1) rowptr[2 * NN] = 2 * EE;
}

// ---------------- GENConv softmax aggregation + residual -------------------
// Channel-split + XCD-pinned quadrants: (ti, ch-half) quadrant q -> XCD pair
// {2q, 2q+1}; per-quadrant gather working set = 2.5 MB < 4 MB L2.
// Quarter-wave (16 lanes x bf16x4) per edge: 4 edges in flight per wave,
// 2x unrolled; reduce via shfl_xor(16,32).
__global__ __launch_bounds__(256) void agg_kernel(
    const __bf16* __restrict__ xin, const int* __restrict__ rowptr,
    const Edge* __restrict__ edges, const float* __restrict__ Wee,
    const float* __restrict__ bee, const float* __restrict__ tptr, int layer,
    __bf16* __restrict__ out) {
  int wave = threadIdx.x >> 6, lane = threadIdx.x & 63;
  int b = blockIdx.x;  // 2500 * 8 blocks
  int x8 = b & 7;
  int q = x8 >> 1;              // quadrant = ti*2 + chh
  int par = x8 & 1;
  int ti = q >> 1, chh = q & 1;
  int group = (b >> 3) * 2 + par;  // 0..4999
  int node = group * 4 + wave;     // 0..19999
  int gnode = ti * NN + node;
  int xrow = ti * MP + node;
  float t2 = tptr[layer] * 1.4426950408889634f;  // fold log2e: exp(mt)=exp2(m*t2)
  int qq = lane >> 4, c15 = lane & 15;
  int c0 = chh * 64 + c15 * 4;
  float w0[4], w1[4], bv[4];
#pragma unroll
  for (int i = 0; i < 4; ++i) {
    w0[i] = Wee[c0 + i];
    w1[i] = Wee[HH + c0 + i];
    bv[i] = bee[c0 + i];
  }
  float den[4] = {}, num[4] = {};
  int e = rowptr[gnode], e1 = rowptr[gnode + 1];

#define MLP4(XV, ED)                                                \
  do {                                                              \
    float eax = (float)(ED).ea0, eay = (float)(ED).ea1;             \
    _Pragma("unroll") for (int i = 0; i < 4; ++i) {                 \
      float m = (float)(XV)[i] + eax * w0[i] + eay * w1[i] + bv[i]; \
      m = fmaxf(m, 0.f) + EPS_MSG;                                  \
      float ex = fexp2(m * t2);                                     \
      den[i] += ex; num[i] += m * ex;                               \
    }                                                               \
  } while (0)

  for (; e + 8 <= e1; e += 8) {
    Edge E0 = edges[e + qq];
    Edge E1 = edges[e + 4 + qq];
    bf16x4 x0 = *(const bf16x4*)(xin + (size_t)E0.src * HH + c0);
    bf16x4 x1 = *(const bf16x4*)(xin + (size_t)E1.src * HH + c0);
    MLP4(x0, E0);
    MLP4(x1, E1);
  }
  if (e + qq < e1) {
    Edge E0 = edges[e + qq];
    bf16x4 x0 = *(const bf16x4*)(xin + (size_t)E0.src * HH + c0);
    MLP4(x0, E0);
  }
  if (e + 4 + qq < e1) {
    Edge E0 = edges[e + 4 + qq];
    bf16x4 x0 = *(const bf16x4*)(xin + (size_t)E0.src * HH + c0);
    MLP4(x0, E0);
  }
#undef MLP4

#pragma unroll
  for (int i = 0; i < 4; ++i) {
    den[i] += __shfl_xor(den[i], 16);
    den[i] += __shfl_xor(den[i], 32);
    num[i] += __shfl_xor(num[i], 16);
    num[i] += __shfl_xor(num[i], 32);
  }
  if (qq == 0) {
    bf16x4 xr = *(const bf16x4*)(xin + (size_t)xrow * HH + c0);
    bf16x4 o;
#pragma unroll
    for (int i = 0; i < 4; ++i)
      o[i] = (__bf16)(num[i] / (den[i] + 1e-16f) + (float)xr[i]);
    *(bf16x4*)(out + (size_t)xrow * HH + c0) = o;
  }
}

// ---------------- fused channel attention (node out + graph partial-pool) --
__global__ __launch_bounds__(256) void attn2_kernel(
    const float* __restrict__ emb, const float* __restrict__ Wq_n,
    const float* __restrict__ Wk_n, const float* __restrict__ Wv_n,
    const float* __restrict__ gn, const float* __restrict__ Wq_g,
    const float* __restrict__ Wk_g, const float* __restrict__ Wv_g,
    const float* __restrict__ gg, __bf16* __restrict__ outn,
    float* __restrict__ partial) {
  __shared__ float gsum[4][256];
  int wave = threadIdx.x >> 6, lane = threadIdx.x & 63;
  int tid = threadIdx.x;
  int n = blockIdx.x * 4 + wave;  // NN % 4 == 0: always valid
  int c0 = lane * 2;
  const float* base = emb + (size_t)n * (2 * HH);
  float2 x0 = *(const float2*)(base + c0);
  float2 x1 = *(const float2*)(base + HH + c0);

#define ATTN_BODY(Wq, Wk, Wv, GAM, O0A, O0B, O1A, O1B)                        \
  {                                                                           \
    float gamma = *(GAM);                                                     \
    float wq00 = Wq[0], wq01 = Wq[1], wq10 = Wq[2], wq11 = Wq[3];             \
    float wk00 = Wk[0], wk01 = Wk[1], wk10 = Wk[2], wk11 = Wk[3];             \
    float wv00 = Wv[0], wv01 = Wv[1], wv10 = Wv[2], wv11 = Wv[3];             \
    float q0a = wq00 * x0.x + wq01 * x1.x, q0b = wq00 * x0.y + wq01 * x1.y;   \
    float q1a = wq10 * x0.x + wq11 * x1.x, q1b = wq10 * x0.y + wq11 * x1.y;   \
    float k0a = wk00 * x0.x + wk01 * x1.x, k0b = wk00 * x0.y + wk01 * x1.y;   \
    float k1a = wk10 * x0.x + wk11 * x1.x, k1b = wk10 * x0.y + wk11 * x1.y;   \
    float v0a = wv00 * x0.x + wv01 * x1.x, v0b = wv00 * x0.y + wv01 * x1.y;   \
    float v1a = wv10 * x0.x + wv11 * x1.x, v1b = wv10 * x0.y + wv11 * x1.y;   \
    float s00 = wave_sum(q0a * k0a + q0b * k0b);                              \
    float s01 = wave_sum(q0a * k1a + q0b * k1b);                              \
    float s10 = wave_sum(q1a * k0a + q1b * k0b);                              \
    float s11 = wave_sum(q1a * k1a + q1b * k1b);                              \
    float m0 = fmaxf(s00, s01);                                               \
    float e00 = __expf(s00 - m0), e01 = __expf(s01 - m0);                     \
    float i0 = 1.f / (e00 + e01);                                             \
    float a00 = e00 * i0, a01 = e01 * i0;                                     \
    float m1 = fmaxf(s10, s11);                                               \
    float e10 = __expf(s10 - m1), e11 = __expf(s11 - m1);                     \
    float i1 = 1.f / (e10 + e11);                                             \
    float a10 = e10 * i1, a11 = e11 * i1;                                     \
    O0A = gamma * (a00 * v0a + a01 * v1a) + x0.x;                             \
    O0B = gamma * (a00 * v0b + a01 * v1b) + x0.y;                             \
    O1A = gamma * (a10 * v0a + a11 * v1a) + x1.x;                             \
    O1B = gamma * (a10 * v0b + a11 * v1b) + x1.y;                             \
  }

  float n0a, n0b, n1a, n1b;
  ATTN_BODY(Wq_n, Wk_n, Wv_n, gn, n0a, n0b, n1a, n1b);
  __bf16* opn = outn + (size_t)n * (2 * HH);
  bf16x2 t0; t0[0] = (__bf16)n0a; t0[1] = (__bf16)n0b;
  bf16x2 t1; t1[0] = (__bf16)n1a; t1[1] = (__bf16)n1b;
  *(bf16x2*)(opn + c0) = t0;
  *(bf16x2*)(opn + HH + c0) = t1;

  float g0a, g0b, g1a, g1b;
  ATTN_BODY(Wq_g, Wk_g, Wv_g, gg, g0a, g0b, g1a, g1b);
  gsum[wave][c0] = g0a;
  gsum[wave][c0 + 1] = g0b;
  gsum[wave][128 + c0] = g1a;
  gsum[wave][129 + c0] = g1b;
  __syncthreads();
  partial[(size_t)blockIdx.x * 256 + tid] =
      gsum[0][tid] + gsum[1][tid] + gsum[2][tid] + gsum[3][tid];
#undef ATTN_BODY
}

// ---------------- pool over per-block partials ----------------
__global__ __launch_bounds__(256) void pool_kernel(const float* __restrict__ partial,
                                                   float* __restrict__ gp_sum,
                                                   int nRows) {
  int c = threadIdx.x;
  float s = 0.f;
  for (int r = blockIdx.x; r < nRows; r += gridDim.x)
    s += partial[(size_t)r * 256 + c];
  atomicAdd(&gp_sum[c], s);
}

// ---------------- graph head (single block) ----------------
__global__ __launch_bounds__(256) void graph_head_kernel(
    const float* __restrict__ gp_sum, const float* __restrict__ Wg1,
    const float* __restrict__ bg1, const float* __restrict__ Wg2,
    const float* __restrict__ bg2, float* __restrict__ outp, float invN) {
  __shared__ float gp[256];
  __shared__ float h1[256];
  __shared__ float lg[2];
  int tid = threadIdx.x;
  gp[tid] = gp_sum[tid] * invN;
  __syncthreads();
  float acc = bg1[tid];
  for (int k = 0; k < 256; ++k) acc += gp[k] * Wg1[k * 256 + tid];
  h1[tid] = fmaxf(acc, 0.f);
  __syncthreads();
  if (tid < 2) {
    float l = bg2[tid];
    for (int c = 0; c < 256; ++c) l += h1[c] * Wg2[c * 2 + tid];
    lg[tid] = l;
  }
  __syncthreads();
  if (tid == 0) {
    float m = fmaxf(lg[0], lg[1]);
    float lse = m + logf(__expf(lg[0] - m) + __expf(lg[1] - m));
    outp[0] = lg[0] - lse;
    outp[1] = lg[1] - lse;
  }
}

// ---------------- launch ----------------
extern "C" void kernel_launch(void* const* d_in, const int* in_sizes, int n_in,
                              void* d_out, int out_size, void* d_ws, size_t ws_size,
                              hipStream_t stream) {
  (void)in_sizes; (void)n_in; (void)out_size; (void)ws_size;
  const float* node_feature = (const float*)d_in[0];
  const int* edge_index = (const int*)d_in[1];
  const float* edge_attr = (const float*)d_in[2];
  const float* Wne = (const float*)d_in[3];
  const float* bne = (const float*)d_in[4];
  const float* Wee = (const float*)d_in[5];
  const float* bee = (const float*)d_in[6];
  const float* W1 = (const float*)d_in[7];
  const float* b1 = (const float*)d_in[8];
  const float* g1 = (const float*)d_in[9];
  const float* be1 = (const float*)d_in[10];
  const float* W2 = (const float*)d_in[11];
  const float* b2 = (const float*)d_in[12];
  const float* dg = (const float*)d_in[13];
  const float* db = (const float*)d_in[14];
  const float* tpar = (const float*)d_in[15];
  const float* Wq_n = (const float*)d_in[16];
  const float* Wk_n = (const float*)d_in[17];
  const float* Wv_n = (const float*)d_in[18];
  const float* gamma_n = (const float*)d_in[19];
  const float* Wn1 = (const float*)d_in[20];
  const float* bn1 = (const float*)d_in[21];
  const float* Wn2 = (const float*)d_in[22];
  const float* bn2 = (const float*)d_in[23];
  const float* Wq_g = (const float*)d_in[24];
  const float* Wk_g = (const float*)d_in[25];
  const float* Wv_g = (const float*)d_in[26];
  const float* gamma_g = (const float*)d_in[27];
  const float* Wg1 = (const float*)d_in[28];
  const float* bg1 = (const float*)d_in[29];
  const float* Wg2 = (const float*)d_in[30];
  const float* bg2 = (const float*)d_in[31];
  float* out = (float*)d_out;

  // ---- workspace carve-out (256B-aligned regions) ----
  char* pc = (char*)d_ws;
  auto alloc = [&](size_t bytes) {
    char* r = pc;
    pc += (bytes + 255) & ~(size_t)255;
    return r;
  };
  float* xbuf = (float*)alloc((size_t)2 * MP * HH * 4);       // f32 residual
  __bf16* hbuf_b = (__bf16*)alloc((size_t)2 * MP * HH * 2);   // LN'd agg input
  __bf16* t256_b = (__bf16*)alloc((size_t)2 * MP * 256 * 2);  // lin1+LN out
  float* emb = (float*)alloc((size_t)NN * 2 * HH * 4);        // [N,T,H] f32
  __bf16* aggout_b = (__bf16*)alloc((size_t)2 * MP * HH * 2); // agg out
  __bf16* nf_b = (__bf16*)emb;  // 23.0MB <= emb(20.5)+aggout(10.3)
  __bf16* attnb = t256_b;       // alias: node-attn out (after last lin2)
  float* partial = xbuf;        // alias: graph-attn partials [5000][256]
  __bf16* wt_ne = (__bf16*)alloc((size_t)128 * 576 * 2);
  __bf16* wt1 = (__bf16*)alloc((size_t)4 * 256 * 128 * 2);
  __bf16* wt2 = (__bf16*)alloc((size_t)4 * 128 * 256 * 2);
  __bf16* wtn1 = (__bf16*)alloc((size_t)256 * 256 * 2);
  float* gp_sum = (float*)alloc(256 * 4);
  int* deg = (int*)alloc((size_t)2 * NN * 4);
  int* cursor = (int*)alloc((size_t)2 * NN * 4);
  int* rowptr = (int*)alloc((size_t)(2 * NN + 2) * 4);
  Edge* edges = (Edge*)alloc((size_t)2 * EE * 8);

  const int gRows2 = 2 * MP / 64;  // 628 row-blocks, stacked GEMMs

  WtDescs wd;
  wd.d[0] = {Wne, wt_ne, FF, HH, 576};
  for (int l = 0; l < 4; ++l)
    wd.d[1 + l] = {W1 + (size_t)l * HH * 256, wt1 + (size_t)l * 256 * HH, HH, 256, HH};
  for (int l = 0; l < 4; ++l)
    wd.d[5 + l] = {W2 + (size_t)l * 256 * HH, wt2 + (size_t)l * HH * 256, 256, HH, 256};
  wd.d[9] = {Wn1, wtn1, 256, 256, 256};

  // prologue: deg zero; converts (vectorized) + degree count + gp_sum zero
  hipMemsetAsync(deg, 0, 2 * NN * sizeof(int), stream);
  prep_kernel<<<NF2B + PADB + WTB + CNTB + 1, 256, 0, stream>>>(
      node_feature, nf_b, wd, edge_index, deg, gp_sum);
  scan2_kernel<<<2, 1024, 0, stream>>>(deg, rowptr, cursor);
  // encoder GEMM (dup to both halves) fused with XCD-routed edge scatter
  enc_scatter_kernel<<<ENCB + 8 * SCB, 256, 0, stream>>>(
      nf_b, wt_ne, bne, hbuf_b, edge_index, edge_attr, cursor, edges);

  // layer loop, both ti at once
  for (int l = 0; l < LL; ++l) {
    agg_kernel<<<2500 * 8, 256, 0, stream>>>(hbuf_b, rowptr, edges, Wee, bee, tpar,
                                             l, aggout_b);
    gemm256<0><<<gRows2, 256, 0, stream>>>(aggout_b, wt1 + (size_t)l * 256 * HH,
                                           b1 + l * 2 * HH, g1 + l * 2 * HH,
                                           be1 + l * 2 * HH, nullptr, nullptr, t256_b,
                                           2 * MP, HH);
    const __bf16* w2l = wt2 + (size_t)l * HH * 256;
    const float* b2l = b2 + l * HH;
    if (l == 0)
      gemm_lin2<0><<<gRows2, 256, 0, stream>>>(t256_b, w2l, b2l, xbuf, dg + 1 * HH,
                                               db + 1 * HH, hbuf_b);
    else if (l < LL - 1)
      gemm_lin2<1><<<gRows2, 256, 0, stream>>>(t256_b, w2l, b2l, xbuf,
                                               dg + (l + 1) * HH, db + (l + 1) * HH,
                                               hbuf_b);
    else
      gemm_lin2<2><<<gRows2, 256, 0, stream>>>(t256_b, w2l, b2l, xbuf, dg, db, emb);
  }

  // fused node+graph attention (one emb read; graph branch -> LDS partials)
  attn2_kernel<<<NN / 4, 256, 0, stream>>>(emb, Wq_n, Wk_n, Wv_n, gamma_n, Wq_g,
                                           Wk_g, Wv_g, gamma_g, attnb, partial);
  // node head: lin1+relu+Wn2+log_softmax fused
  gemm256<1><<<MP / 64, 256, 0, stream>>>(attnb, wtn1, bn1, nullptr, nullptr, Wn2,
                                          bn2, out, NN, 256);
  // graph head
  pool_kernel<<<128, 256, 0, stream>>>(partial, gp_sum, NN / 4);
  graph_head_kernel<<<1, 256, 0, stream>>>(gp_sum, Wg1, bg1, Wg2, bg2,
                                           out + (size_t)NN * CN, 1.0f / NN);
}